// Round 1
// baseline (183.999 us; speedup 1.0000x reference)
//
#include <hip/hip_runtime.h>
#include <stdint.h>

// Problem constants (from reference)
#define B_   16
#define D_   256
#define T_   4096
#define K_   1024
#define N_   (B_ * T_)          // 65536 points
#define BM   128                // points per block
#define KT   16                 // codes per k-tile
#define NKT  (K_ / KT)          // 64 k-tiles
#define XPITCH 264              // LDS row pitch for x tile (elements, +8 pad -> 528B rows, 16B aligned)
#define EPITCH 264              // LDS row pitch for emb tile

typedef __attribute__((ext_vector_type(8))) short short8;   // 8 bf16 = MFMA A/B frag
typedef __attribute__((ext_vector_type(4))) float floatx4;  // MFMA C/D frag

static __device__ __forceinline__ unsigned short f2bf(float f) {
    // round-to-nearest-even fp32 -> bf16
    unsigned u = __float_as_uint(f);
    unsigned r = u + 0x7fffu + ((u >> 16) & 1u);
    return (unsigned short)(r >> 16);
}

// Kernel 0: emb fp32 -> bf16, and esqh[k] = 0.5 * sum_d emb[k][d]^2
__global__ __launch_bounds__(64) void emb_prep(const float* __restrict__ emb,
                                               unsigned short* __restrict__ embb,
                                               float* __restrict__ esqh) {
    int k = blockIdx.x;          // one wave per code row
    int lane = threadIdx.x;      // 0..63
    const float4* src = (const float4*)(emb + (size_t)k * D_);
    float4 v = src[lane];        // 4 consecutive d per lane
    ushort4 o;
    o.x = f2bf(v.x); o.y = f2bf(v.y); o.z = f2bf(v.z); o.w = f2bf(v.w);
    ((ushort4*)embb)[(size_t)k * 64 + lane] = o;
    float ss = v.x * v.x + v.y * v.y + v.z * v.z + v.w * v.w;
    #pragma unroll
    for (int off = 32; off; off >>= 1) ss += __shfl_xor(ss, off, 64);
    if (lane == 0) esqh[k] = 0.5f * ss;
}

// Main kernel: per block of 128 points: bf16 MFMA scores vs all 1024 codes,
// fused argmin, then gather/transpose write + loss partial.
__global__ __launch_bounds__(256) void vq_main(const float* __restrict__ z,
                                               const float* __restrict__ emb,
                                               const unsigned short* __restrict__ embb,
                                               const float* __restrict__ esqh,
                                               float* __restrict__ out0,
                                               float* __restrict__ lossp) {
    __shared__ __align__(16) unsigned short xs[BM * XPITCH];   // 67584 B: x tile bf16 [t][d]
    __shared__ __align__(16) unsigned short es[KT * EPITCH];   //  8448 B: emb tile bf16 [code][d]
    __shared__ int   pidx[BM];
    __shared__ float lred[4];

    int tid = threadIdx.x;
    int blk = blockIdx.x;
    int b   = blk >> 5;                 // 32 blocks per batch (T/BM = 32)
    int t0  = (blk & 31) * BM;
    const float* zb = z + (size_t)b * D_ * T_ + t0;

    // ---- Phase 1: load z tile [d][t], convert bf16, transpose into xs[t][d] ----
    {
        int t  = tid & 127;
        int ph = tid >> 7;              // 0..1
        #pragma unroll 4
        for (int j = 0; j < 64; ++j) {
            int p = ph + 2 * j;         // d-pair index 0..127
            int d = p * 2;
            float a0 = zb[(size_t)d * T_ + t];
            float a1 = zb[(size_t)(d + 1) * T_ + t];
            unsigned pack = (unsigned)f2bf(a0) | ((unsigned)f2bf(a1) << 16);
            *(unsigned*)&xs[t * XPITCH + d] = pack;   // 4B aligned (d even)
        }
    }
    __syncthreads();

    // ---- Phase 2: load persistent A fragments (2 sets of 16 points per wave) ----
    int lane = tid & 63;
    int w    = tid >> 6;                // wave 0..3
    int ml   = lane & 15;
    int quad = lane >> 4;
    short8 afr[2][8];
    #pragma unroll
    for (int set = 0; set < 2; ++set) {
        int p = w * 32 + set * 16 + ml;
        #pragma unroll
        for (int s = 0; s < 8; ++s)
            afr[set][s] = *(const short8*)&xs[p * XPITCH + s * 32 + quad * 8];
    }

    // prefetch emb tile 0 into registers (8192 B per tile, 2x uint4 per thread)
    uint4 r0, r1;
    {
        const uint4* src = (const uint4*)embb;      // tile kt = uint4 [kt*512, +512)
        r0 = src[tid];
        r1 = src[tid + 256];
    }

    float bv[2][4];
    int   bi[2][4];
    #pragma unroll
    for (int s = 0; s < 2; ++s)
        #pragma unroll
        for (int i = 0; i < 4; ++i) { bv[s][i] = 1e30f; bi[s][i] = 0; }

    // ---- Phase 3: k-loop over 64 tiles of 16 codes ----
    for (int kt = 0; kt < NKT; ++kt) {
        // write staged tile regs -> LDS (row = li>>5, 32 uint4 of payload per row)
        {
            int li = tid, row = li >> 5, off = li & 31;
            *(uint4*)&es[row * EPITCH + off * 8] = r0;
            li = tid + 256; row = li >> 5; off = li & 31;
            *(uint4*)&es[row * EPITCH + off * 8] = r1;
        }
        __syncthreads();
        if (kt + 1 < NKT) {   // prefetch next tile; stays in flight over the MFMAs
            const uint4* src = (const uint4*)embb + (size_t)(kt + 1) * 512;
            r0 = src[tid];
            r1 = src[tid + 256];
        }
        floatx4 acc0 = {0.f, 0.f, 0.f, 0.f};
        floatx4 acc1 = {0.f, 0.f, 0.f, 0.f};
        #pragma unroll
        for (int s = 0; s < 8; ++s) {
            short8 bf = *(const short8*)&es[ml * EPITCH + s * 32 + quad * 8];
            acc0 = __builtin_amdgcn_mfma_f32_16x16x32_bf16(afr[0][s], bf, acc0, 0, 0, 0);
            acc1 = __builtin_amdgcn_mfma_f32_16x16x32_bf16(afr[1][s], bf, acc1, 0, 0, 0);
        }
        // epilogue: dist/2 = 0.5*||e||^2 - score ; C layout: col(code)=lane&15, row=quad*4+i
        int c = kt * KT + ml;
        float eh = esqh[c];
        #pragma unroll
        for (int i = 0; i < 4; ++i) {
            float v0 = eh - acc0[i];
            if (v0 < bv[0][i]) { bv[0][i] = v0; bi[0][i] = c; }
            float v1 = eh - acc1[i];
            if (v1 < bv[1][i]) { bv[1][i] = v1; bi[1][i] = c; }
        }
        __syncthreads();   // protect es before next iteration's write
    }

    // ---- reduce argmin across the 16 code-lanes of each quad ----
    #pragma unroll
    for (int set = 0; set < 2; ++set) {
        #pragma unroll
        for (int i = 0; i < 4; ++i) {
            float v = bv[set][i];
            int  ii = bi[set][i];
            #pragma unroll
            for (int off = 1; off < 16; off <<= 1) {
                float ov = __shfl_xor(v, off, 64);
                int   oi = __shfl_xor(ii, off, 64);
                if (ov < v || (ov == v && oi < ii)) { v = ov; ii = oi; }
            }
            if (ml == 0) pidx[w * 32 + set * 16 + quad * 4 + i] = ii;
        }
    }
    __syncthreads();

    // ---- Phase 4: gather emb rows (fp32), transpose-write out0, loss partial ----
    float lsum = 0.f;
    {
        int t  = tid & 127;
        int dg = tid >> 7;              // 0..1 (d parity)
        int code = pidx[t];
        const float* er = emb + (size_t)code * D_;
        float* ob = out0 + (size_t)b * D_ * T_ + t0;
        #pragma unroll 4
        for (int j = 0; j < 128; ++j) {
            int d = dg + 2 * j;
            float q  = er[d];
            float zv = zb[(size_t)d * T_ + t];
            ob[(size_t)d * T_ + t] = q;
            float df = q - zv;
            lsum = fmaf(df, df, lsum);
        }
    }
    #pragma unroll
    for (int off = 32; off; off >>= 1) lsum += __shfl_xor(lsum, off, 64);
    if (lane == 0) lred[w] = lsum;
    __syncthreads();
    if (tid == 0) {
        float s = lred[0] + lred[1] + lred[2] + lred[3];
        atomicAdd(lossp, s * (1.25f / 16777216.0f));   // 1.25 / (N*D)
    }
}

extern "C" void kernel_launch(void* const* d_in, const int* in_sizes, int n_in,
                              void* d_out, int out_size, void* d_ws, size_t ws_size,
                              hipStream_t stream) {
    (void)in_sizes; (void)n_in; (void)out_size; (void)ws_size;
    const float* z   = (const float*)d_in[0];
    const float* emb = (const float*)d_in[1];

    unsigned short* embb = (unsigned short*)d_ws;                       // 512 KiB
    float* esqh = (float*)((char*)d_ws + (size_t)K_ * D_ * 2);          // 4 KiB

    float* out0  = (float*)d_out;
    float* lossp = out0 + (size_t)N_ * D_;

    hipMemsetAsync(lossp, 0, sizeof(float), stream);                    // out re-poisoned each replay
    emb_prep<<<K_, 64, 0, stream>>>(emb, embb, esqh);
    vq_main<<<N_ / BM, 256, 0, stream>>>(z, emb, embb, esqh, out0, lossp);
}

// Round 2
// 148.029 us; speedup vs baseline: 1.2430x; 1.2430x over previous
//
#include <hip/hip_runtime.h>
#include <stdint.h>

// Problem constants
#define B_   16
#define D_   256
#define T_   4096
#define K_   1024
#define N_   (B_ * T_)      // 65536 points
#define BM   64             // points per block
#define NKT  64             // 64 k-tiles of 16 codes

typedef __attribute__((ext_vector_type(4))) float floatx4;
typedef __attribute__((ext_vector_type(2))) float floatx2;

// ---- Kernel 0: emb fp32 -> fp8 e4m3 (scaled x1024), esqh = 512*||e||^2 (scaled objective), zero loss ----
__global__ __launch_bounds__(256) void emb_prep(const float* __restrict__ emb,
                                                uint32_t* __restrict__ embf8,
                                                float* __restrict__ esqh,
                                                float* __restrict__ lossp) {
    int w = threadIdx.x >> 6, lane = threadIdx.x & 63;
    int k = blockIdx.x * 4 + w;                       // one wave per code row
    float4 v = ((const float4*)emb)[k * 64 + lane];   // 4 consecutive d
    float a0 = v.x * 1024.f, a1 = v.y * 1024.f, a2 = v.z * 1024.f, a3 = v.w * 1024.f;
    int p = __builtin_amdgcn_cvt_pk_fp8_f32(a0, a1, 0, false);   // bytes 0,1
    p = __builtin_amdgcn_cvt_pk_fp8_f32(a2, a3, p, true);        // bytes 2,3
    embf8[k * 64 + lane] = (uint32_t)p;
    float ss = a0 * a0 + a1 * a1 + a2 * a2 + a3 * a3;
    #pragma unroll
    for (int off = 32; off; off >>= 1) ss += __shfl_xor(ss, off, 64);
    if (lane == 0) esqh[k] = ss * (0.5f / 1024.f);    // = 1024 * 0.5*||e||^2
    if (blockIdx.x == 0 && threadIdx.x == 0) *lossp = 0.f;
}

// ---- Main kernel ----
// LDS xs swizzle (phases 1-3): byte offset of d in row t:
//   c = d>>4, h = (d>>3)&1 -> ((c ^ (t&15))<<4) + ((h ^ ((t>>4)&1))<<3) + (d&7)
// -> every b64 access pattern lands exactly 4 words/bank (verified per phase).
// Phase 4 reuses xs with a plain 16B-chunk swizzle: chunk g at ((g ^ (t&15))<<4).
__global__ __launch_bounds__(256, 4) void vq_main(const float* __restrict__ z,
                                                  const uint32_t* __restrict__ embf8,
                                                  const float* __restrict__ esqh,
                                                  float* __restrict__ out0,
                                                  float* __restrict__ lossp) {
    __shared__ __align__(16) unsigned char xs[BM * 256];      // 16 KiB: x fp8 [t][d] swizzled
    __shared__ __align__(16) unsigned char es[2][16 * 256];   //  8 KiB: double-buffered code tile
    __shared__ int   pidx[BM];
    __shared__ float lred[4];

    int tid  = threadIdx.x;
    int lane = tid & 63, w = tid >> 6;
    int ml   = lane & 15, quad = lane >> 4;
    int blk  = blockIdx.x;
    int b    = blk >> 6;                  // 64 blocks per batch (T/BM)
    int t0   = (blk & 63) * BM;
    const float* zb = z + (size_t)b * (D_ * T_) + t0;

    // ---- Phase 1: load z [d][t], convert fp8, store transposed+swizzled ----
    {
        int t = lane;
        int hf = (t >> 4) & 1;
        #pragma unroll 2
        for (int j = 0; j < 8; ++j) {
            int dgrp = w + 4 * j;          // 0..31 (8 consecutive d each)
            int d0 = dgrp * 8;
            float f0 = zb[(d0 + 0) * T_ + t];
            float f1 = zb[(d0 + 1) * T_ + t];
            float f2 = zb[(d0 + 2) * T_ + t];
            float f3 = zb[(d0 + 3) * T_ + t];
            float f4 = zb[(d0 + 4) * T_ + t];
            float f5 = zb[(d0 + 5) * T_ + t];
            float f6 = zb[(d0 + 6) * T_ + t];
            float f7 = zb[(d0 + 7) * T_ + t];
            uint32_t p0 = (uint32_t)__builtin_amdgcn_cvt_pk_fp8_f32(f0, f1, 0, false);
            p0 = (uint32_t)__builtin_amdgcn_cvt_pk_fp8_f32(f2, f3, (int)p0, true);
            uint32_t p1 = (uint32_t)__builtin_amdgcn_cvt_pk_fp8_f32(f4, f5, 0, false);
            p1 = (uint32_t)__builtin_amdgcn_cvt_pk_fp8_f32(f6, f7, (int)p1, true);
            int c = dgrp >> 1, h = dgrp & 1;
            int off = ((c ^ (t & 15)) << 4) + ((h ^ hf) << 3);
            *(uint2*)&xs[t * 256 + off] = make_uint2(p0, p1);
        }
    }
    __syncthreads();

    // ---- Phase 2: persistent A fragments (16 points per wave) ----
    long afr[8];
    {
        int p = w * 16 + ml;
        int flip = w & 1;                  // (p>>4)&1
        #pragma unroll
        for (int kk = 0; kk < 8; ++kk) {
            int c = 2 * kk + (quad >> 1), h = quad & 1;
            int off = ((c ^ ml) << 4) + ((h ^ flip) << 3);
            afr[kk] = *(const long*)&xs[p * 256 + off];
        }
    }

    // es read offsets (constant across kt) and staging write offset
    int eoff[8];
    #pragma unroll
    for (int kk = 0; kk < 8; ++kk) {
        int c = 2 * kk + (quad >> 1), h = quad & 1;
        eoff[kk] = ml * 256 + ((c ^ ml) << 4) + (h << 3);
    }
    const int eswoff = (tid >> 4) * 256 + (((tid & 15) ^ (tid >> 4)) << 4);

    // stage tile 0 into buf0, prefetch tile 1
    *(uint4*)&es[0][eswoff] = ((const uint4*)embf8)[tid];
    uint4 r0 = ((const uint4*)embf8)[256 + tid];
    __syncthreads();

    float bv[4]; int bi[4];
    #pragma unroll
    for (int i = 0; i < 4; ++i) { bv[i] = 1e30f; bi[i] = 0; }

    // ---- Phase 3: k-loop, 1 barrier per tile (double-buffered es) ----
    #pragma unroll 2
    for (int kt = 0; kt < NKT; ++kt) {
        int cur = kt & 1;
        if (kt + 1 < NKT) *(uint4*)&es[cur ^ 1][eswoff] = r0;
        if (kt + 2 < NKT) r0 = ((const uint4*)embf8)[(kt + 2) * 256 + tid];
        float eh = esqh[kt * 16 + ml];
        floatx4 acc = {0.f, 0.f, 0.f, 0.f};
        #pragma unroll
        for (int kk = 0; kk < 8; ++kk) {
            long bf = *(const long*)&es[cur][eoff[kk]];
            acc = __builtin_amdgcn_mfma_f32_16x16x32_fp8_fp8(afr[kk], bf, acc, 0, 0, 0);
        }
        // scaled dist = 1024*(0.5||e||^2 - x.e); C layout: code = lane&15, point row = quad*4+i
        int c = kt * 16 + ml;
        #pragma unroll
        for (int i = 0; i < 4; ++i) {
            float v = eh - acc[i];
            if (v < bv[i]) { bv[i] = v; bi[i] = c; }
        }
        __syncthreads();
    }

    // ---- argmin across the 16 code-lanes of each quad ----
    #pragma unroll
    for (int i = 0; i < 4; ++i) {
        float v = bv[i]; int ii = bi[i];
        #pragma unroll
        for (int off = 1; off < 16; off <<= 1) {
            float ov = __shfl_xor(v, off, 64);
            int   oi = __shfl_xor(ii, off, 64);
            if (ov < v || (ov == v && oi < ii)) { v = ov; ii = oi; }
        }
        if (ml == 0) pidx[w * 16 + quad * 4 + i] = ii;
    }
    __syncthreads();

    // ---- Phase 4a: gather chosen fp8 rows into xs (coalesced), 16B-chunk swizzle ----
    #pragma unroll
    for (int m = 0; m < 4; ++m) {
        int t   = (tid >> 4) + 16 * m;
        int off = tid & 15;
        int code = pidx[t];
        uint4 v = ((const uint4*)embf8)[code * 16 + off];
        *(uint4*)&xs[t * 256 + ((off ^ (t & 15)) << 4)] = v;
    }
    __syncthreads();

    // ---- Phase 4b: dequant, transpose-write out, loss partial ----
    float lsum = 0.f;
    float* ob = out0 + (size_t)b * (D_ * T_) + t0;
    {
        int t = lane;
        #pragma unroll
        for (int j = 0; j < 4; ++j) {
            int g = w + 4 * j;            // 16-d group, 0..15
            uint4 v = *(const uint4*)&xs[t * 256 + ((g ^ (t & 15)) << 4)];
            uint32_t wd[4] = {v.x, v.y, v.z, v.w};
            #pragma unroll
            for (int u = 0; u < 4; ++u) {
                floatx2 lo = __builtin_amdgcn_cvt_pk_f32_fp8((int)wd[u], false);
                floatx2 hi = __builtin_amdgcn_cvt_pk_f32_fp8((int)wd[u], true);
                float q[4] = {lo[0] * (1.f/1024.f), lo[1] * (1.f/1024.f),
                              hi[0] * (1.f/1024.f), hi[1] * (1.f/1024.f)};
                #pragma unroll
                for (int s = 0; s < 4; ++s) {
                    int d = g * 16 + u * 4 + s;
                    float zv = zb[d * T_ + t];
                    ob[d * T_ + t] = q[s];
                    float df = q[s] - zv;
                    lsum = fmaf(df, df, lsum);
                }
            }
        }
    }
    #pragma unroll
    for (int off = 32; off; off >>= 1) lsum += __shfl_xor(lsum, off, 64);
    if (lane == 0) lred[w] = lsum;
    __syncthreads();
    if (tid == 0)
        atomicAdd(lossp, (lred[0] + lred[1] + lred[2] + lred[3]) * (1.25f / 16777216.0f));
}

extern "C" void kernel_launch(void* const* d_in, const int* in_sizes, int n_in,
                              void* d_out, int out_size, void* d_ws, size_t ws_size,
                              hipStream_t stream) {
    (void)in_sizes; (void)n_in; (void)out_size; (void)ws_size;
    const float* z   = (const float*)d_in[0];
    const float* emb = (const float*)d_in[1];

    uint32_t* embf8 = (uint32_t*)d_ws;                              // 256 KiB
    float*    esqh  = (float*)((char*)d_ws + (size_t)K_ * D_);      // 4 KiB

    float* out0  = (float*)d_out;
    float* lossp = out0 + (size_t)N_ * D_;

    emb_prep<<<K_ / 4, 256, 0, stream>>>(emb, embf8, esqh, lossp);
    vq_main<<<N_ / BM, 256, 0, stream>>>(z, embf8, esqh, out0, lossp);
}